// Round 16
// baseline (138.215 us; speedup 1.0000x reference)
//
#include <hip/hip_runtime.h>

// Problem dims
constexpr int SEQ   = 2048;
constexpr int BATCH = 2;
constexpr int EMB   = 1024;
constexpr int NH    = 16;
constexpr int HDIM  = 64;
constexpr int MROWS = SEQ * BATCH;   // 4096
constexpr int KDIM  = EMB;           // 1024
constexpr int NCOLS = 3 * EMB;       // 3072

typedef __bf16 bf16x8 __attribute__((ext_vector_type(8)));
typedef __bf16 bf16x4 __attribute__((ext_vector_type(4)));
typedef float  f32x4  __attribute__((ext_vector_type(4)));
typedef float  f32x16 __attribute__((ext_vector_type(16)));
typedef unsigned int u32;
typedef unsigned int u32x4 __attribute__((ext_vector_type(4)));

__device__ __forceinline__ u32 cvt_pk_bf16(float lo, float hi) {
  u32 r;
  asm("v_cvt_pk_bf16_f32 %0, %1, %2" : "=v"(r) : "v"(lo), "v"(hi));
  return r;
}
__device__ __forceinline__ void pl32_swap(u32& a, u32& b) {
  asm("v_permlane32_swap_b32 %0, %1" : "+v"(a), "+v"(b));
}
// async global->LDS, 16B per lane; LDS dest = wave-uniform base + lane*16
__device__ __forceinline__ void g2l16(const __bf16* g, __bf16* l) {
  __builtin_amdgcn_global_load_lds(
      (const __attribute__((address_space(1))) void*)g,
      (__attribute__((address_space(3))) void*)l, 16, 0, 0);
}

// ---------------------------------------------------------------------------
// fp32 -> bf16 cast for BOTH x and Wqkv in one launch
// ---------------------------------------------------------------------------
constexpr int N4X = (MROWS * KDIM) / 4;   // 1048576
constexpr int N4W = (NCOLS * KDIM) / 4;   // 786432
__global__ __launch_bounds__(256) void cvt_all(
    const float* __restrict__ x, const float* __restrict__ Wq,
    __bf16* __restrict__ Xb, __bf16* __restrict__ Wb) {
  int stride = gridDim.x * blockDim.x;
  for (int i = blockIdx.x * blockDim.x + threadIdx.x; i < N4X + N4W; i += stride) {
    const float4 v = (i < N4X) ? reinterpret_cast<const float4*>(x)[i]
                               : reinterpret_cast<const float4*>(Wq)[i - N4X];
    bf16x4 o;
    o[0] = (__bf16)v.x; o[1] = (__bf16)v.y; o[2] = (__bf16)v.z; o[3] = (__bf16)v.w;
    if (i < N4X) reinterpret_cast<bf16x4*>(Xb)[i] = o;
    else         reinterpret_cast<bf16x4*>(Wb)[i - N4X] = o;
  }
}

// ---------------------------------------------------------------------------
// QKV projection (R4/R9-exact: BK=32, 2-phase dbuf gload_lds staging, 4x24
// XCD chunking). Single delta: launch_bounds min-blocks 4 -> 5 (32KB LDS x 5
// = 160KB pool exactly; VGPR 88 < 102, no spill pressure) for +25% staging
// latency hiding. If 5 doesn't fit, HW falls back to 4 = verified config.
// ---------------------------------------------------------------------------
__global__ __launch_bounds__(256, 5) void qkv_gemm(
    const __bf16* __restrict__ Xb, const __bf16* __restrict__ Wb,
    const float* __restrict__ bqkv,
    __bf16* __restrict__ Qb, __bf16* __restrict__ Kb, __bf16* __restrict__ Vt) {
  __shared__ __attribute__((aligned(16))) __bf16 Al[2][128 * 32];
  __shared__ __attribute__((aligned(16))) __bf16 Bl[2][128 * 32];

  const int tid  = threadIdx.x;
  const int lane = tid & 63;
  const int w    = tid >> 6;
  const int wm   = w >> 1, wn = w & 1;

  // bijective XCD chunking (R4/R9-verified): 768 blocks, 96 per XCD = 4x24
  const int bid  = blockIdx.x;
  const int wgid = (bid & 7) * 96 + (bid >> 3);
  const int nx   = wgid % 24;
  const int nyy  = wgid / 24;
  const int m0   = nyy * 128;
  const int n0   = nx * 128;

  f32x4 acc[4][4] = {};

  auto stage = [&](int buf, int kt) {
#pragma unroll
    for (int c = 0; c < 2; ++c) {
      const int u   = (w * 2 + c) * 64 + lane;
      const int row = u >> 2;
      const int sc  = ((u & 3) ^ ((row >> 1) & 3)) * 8;
      g2l16(&Xb[(size_t)(m0 + row) * KDIM + kt * 32 + sc], &Al[buf][(w * 2 + c) * 512]);
      g2l16(&Wb[(size_t)(n0 + row) * KDIM + kt * 32 + sc], &Bl[buf][(w * 2 + c) * 512]);
    }
  };

  stage(0, 0);
  __syncthreads();

  const int l15 = lane & 15, hi4 = lane >> 4;
  const int cswz = (hi4 ^ ((l15 >> 1) & 3)) * 8;

  for (int kt = 0; kt < KDIM / 32; ++kt) {
    const int buf = kt & 1;
    if (kt + 1 < KDIM / 32) stage(buf ^ 1, kt + 1);

    bf16x8 af[4], bfr[4];
#pragma unroll
    for (int i = 0; i < 4; ++i) {
      af[i]  = *reinterpret_cast<const bf16x8*>(&Al[buf][(wm * 64 + i * 16 + l15) * 32 + cswz]);
      bfr[i] = *reinterpret_cast<const bf16x8*>(&Bl[buf][(wn * 64 + i * 16 + l15) * 32 + cswz]);
    }
    __builtin_amdgcn_s_setprio(1);
#pragma unroll
    for (int i = 0; i < 4; ++i)
#pragma unroll
      for (int j = 0; j < 4; ++j)
        acc[i][j] = __builtin_amdgcn_mfma_f32_16x16x32_bf16(af[i], bfr[j], acc[i][j], 0, 0, 0);
    __builtin_amdgcn_s_setprio(0);
    __syncthreads();
  }

  const float QSCALE = 0.18033688011112042f;  // 0.125 * log2(e)
#pragma unroll
  for (int j = 0; j < 4; ++j) {
    const int f    = n0 + wn * 64 + j * 16 + l15;
    const float bias = bqkv[f];
    const int sec  = f >> 10;
    const int hd   = f & 1023;
    const int h    = hd >> 6, d = hd & 63;
#pragma unroll
    for (int i = 0; i < 4; ++i) {
#pragma unroll
      for (int r = 0; r < 4; ++r) {
        const int mm = m0 + wm * 64 + i * 16 + hi4 * 4 + r;
        const int s_ = mm >> 1, b_ = mm & 1;
        const int bh = b_ * NH + h;
        const float val = acc[i][j][r] + bias;
        if (sec == 0) {
          Qb[((size_t)bh * SEQ + s_) * HDIM + d] = (__bf16)(val * QSCALE);
        } else if (sec == 1) {
          Kb[((size_t)bh * SEQ + s_) * HDIM + d] = (__bf16)val;
        } else {
          Vt[((size_t)bh * HDIM + d) * SEQ + s_] = (__bf16)val;
        }
      }
    }
  }
}

// ---------------------------------------------------------------------------
// Flash attention (R12-exact, verified 57.0us / absmax 0.0029): 4 waves x
// 32 q-rows, KVBLK=64 double-buffered gload_lds staging, setprio fences
// (load-bearing — R8), max-free softmax + ones-row MFMA denominator.
// ---------------------------------------------------------------------------
__global__ __launch_bounds__(256) void attn_fwd(
    const __bf16* __restrict__ Qb, const __bf16* __restrict__ Kb,
    const __bf16* __restrict__ Vt, float* __restrict__ out) {
  __shared__ __attribute__((aligned(16))) __bf16 lds[16384];  // 2 x (K 8KB + V 8KB)

  const int tid  = threadIdx.x;
  const int lane = tid & 63;
  const int w    = tid >> 6;   // 0..3
  const int lq   = lane & 31;
  const int hi   = lane >> 5;

  // bijective XCD swizzle: 512 blocks, 64 per XCD -> 4 consecutive bh per XCD
  const int bid  = blockIdx.x;
  const int wgid = (bid & 7) * 64 + (bid >> 3);
  const int qi   = wgid & 15;
  const int bh   = wgid >> 4;
  const int b_   = bh >> 4, h = bh & 15;
  const int q0   = qi * 128 + w * 32;

  const __bf16* Qp = Qb + (size_t)bh * SEQ * HDIM;
  const __bf16* Kp = Kb + (size_t)bh * SEQ * HDIM;
  const __bf16* Vp = Vt + (size_t)bh * HDIM * SEQ;

  // Q persistent: QK^T B-operand, col q=lane&31, k(d)=ks*16+hi*8+j
  bf16x8 qf[4];
#pragma unroll
  for (int ks = 0; ks < 4; ++ks)
    qf[ks] = *reinterpret_cast<const bf16x8*>(&Qp[(size_t)(q0 + lq) * HDIM + ks * 16 + hi * 8]);

  // all-ones A-operand for the denominator MFMA
  bf16x8 ones;
#pragma unroll
  for (int i = 0; i < 8; ++i) ones[i] = (__bf16)1.0f;

  f32x16 acc0 = {}, acc1 = {}, accL = {};

  auto stage = [&](int b, int t0) {
#pragma unroll
    for (int c = 0; c < 2; ++c) {
      const int u   = (w * 2 + c) * 64 + lane;            // 0..511 chunks
      const int row = u >> 3;
      const int sc  = ((u & 7) * 8) ^ ((row & 7) << 3);
      g2l16(Kp + (size_t)(t0 + row) * HDIM + sc, lds + b * 8192 + (w * 2 + c) * 512);
      g2l16(Vp + (size_t)row * SEQ + t0 + sc,    lds + b * 8192 + 4096 + (w * 2 + c) * 512);
    }
  };

  stage(0, 0);
  __syncthreads();
  int cur = 0;

  for (int t0 = 0; t0 < SEQ; t0 += 64) {
    if (t0 + 64 < SEQ) stage(cur ^ 1, t0 + 64);  // prefetch flies under compute
    const __bf16* kb = lds + cur * 8192;
    const __bf16* vb = kb + 4096;

    // ---- S = K·Q^T : two 32x32 t-blocks, 4 k-steps over d ----
    f32x16 S0 = {}, S1 = {};
    __builtin_amdgcn_s_setprio(1);
#pragma unroll
    for (int ks = 0; ks < 4; ++ks) {
      const int colb = ks * 16 + hi * 8;
      bf16x8 k0 = *reinterpret_cast<const bf16x8*>(&kb[lq * 64        + (colb ^ ((lq & 7) << 3))]);
      bf16x8 k1 = *reinterpret_cast<const bf16x8*>(&kb[(32 + lq) * 64 + (colb ^ ((lq & 7) << 3))]);
      S0 = __builtin_amdgcn_mfma_f32_32x32x16_bf16(k0, qf[ks], S0, 0, 0, 0);
      S1 = __builtin_amdgcn_mfma_f32_32x32x16_bf16(k1, qf[ks], S1, 0, 0, 0);
    }
    __builtin_amdgcn_s_setprio(0);

    // ---- max-free softmax: P = exp2(S) (no sums — MFMA computes l) ----
#pragma unroll
    for (int i = 0; i < 16; ++i) S0[i] = __builtin_amdgcn_exp2f(S0[i]);
#pragma unroll
    for (int i = 0; i < 16; ++i) S1[i] = __builtin_amdgcn_exp2f(S1[i]);

    // ---- P -> bf16 B-fragments for PV (cvt_pk + permlane32_swap) ----
    bf16x8 pw[4];
    {
      auto mk = [&](const f32x16& P, bf16x8* dst) {
#pragma unroll
        for (int kk = 0; kk < 2; ++kk) {
          u32 a0 = cvt_pk_bf16(P[kk * 8 + 0], P[kk * 8 + 1]);
          u32 b0 = cvt_pk_bf16(P[kk * 8 + 4], P[kk * 8 + 5]);
          u32 a1 = cvt_pk_bf16(P[kk * 8 + 2], P[kk * 8 + 3]);
          u32 b1 = cvt_pk_bf16(P[kk * 8 + 6], P[kk * 8 + 7]);
          pl32_swap(a0, b0);
          pl32_swap(a1, b1);
          u32x4 wv; wv[0] = a0; wv[1] = a1; wv[2] = b0; wv[3] = b1;
          dst[kk] = __builtin_bit_cast(bf16x8, wv);
        }
      };
      mk(S0, &pw[0]);
      mk(S1, &pw[2]);
    }

    // ---- O^T += V^T·P^T and l += 1·P^T : 4 k-steps over t ----
    __builtin_amdgcn_s_setprio(1);
#pragma unroll
    for (int ks = 0; ks < 4; ++ks) {
      const int colb = ks * 16 + hi * 8;
      bf16x8 v0 = *reinterpret_cast<const bf16x8*>(&vb[lq * 64        + (colb ^ ((lq & 7) << 3))]);
      bf16x8 v1 = *reinterpret_cast<const bf16x8*>(&vb[(32 + lq) * 64 + (colb ^ ((lq & 7) << 3))]);
      acc0 = __builtin_amdgcn_mfma_f32_32x32x16_bf16(v0, pw[ks], acc0, 0, 0, 0);
      acc1 = __builtin_amdgcn_mfma_f32_32x32x16_bf16(v1, pw[ks], acc1, 0, 0, 0);
      accL = __builtin_amdgcn_mfma_f32_32x32x16_bf16(ones, pw[ks], accL, 0, 0, 0);
    }
    __builtin_amdgcn_s_setprio(0);

    __syncthreads();  // readers done with cur + prefetch arrived
    cur ^= 1;
  }

  // ---- epilogue: accL[0] == l[q] exactly; no shfl needed ----
  const float inv = 1.0f / accL[0];
  const int s_ = q0 + lq;
  float* op = out + ((size_t)s_ * BATCH + b_) * EMB + h * HDIM;
#pragma unroll
  for (int rr = 0; rr < 4; ++rr) {
    float4 o0 = {acc0[4 * rr] * inv, acc0[4 * rr + 1] * inv,
                 acc0[4 * rr + 2] * inv, acc0[4 * rr + 3] * inv};
    *reinterpret_cast<float4*>(&op[8 * rr + 4 * hi]) = o0;
    float4 o1 = {acc1[4 * rr] * inv, acc1[4 * rr + 1] * inv,
                 acc1[4 * rr + 2] * inv, acc1[4 * rr + 3] * inv};
    *reinterpret_cast<float4*>(&op[8 * rr + 4 * hi + 32]) = o1;
  }
}

// ---------------------------------------------------------------------------
extern "C" void kernel_launch(void* const* d_in, const int* in_sizes, int n_in,
                              void* d_out, int out_size, void* d_ws, size_t ws_size,
                              hipStream_t stream) {
  (void)in_sizes; (void)n_in; (void)out_size; (void)ws_size;
  const float* x    = (const float*)d_in[0];
  const float* Wqkv = (const float*)d_in[1];
  const float* bias = (const float*)d_in[2];
  float* out = (float*)d_out;

  char* ws = (char*)d_ws;
  __bf16* Xb = (__bf16*)(ws);                 //  8 MB  [M][K]
  __bf16* Wb = (__bf16*)(ws + 8388608);       //  6 MB  [N][K]
  __bf16* Qb = (__bf16*)(ws + 14680064);      //  8 MB  [b,h,s,d] (pre-scaled)
  __bf16* Kb = (__bf16*)(ws + 23068672);      //  8 MB  [b,h,s,d]
  __bf16* Vt = (__bf16*)(ws + 31457280);      //  8 MB  [b,h,d,s]

  cvt_all<<<dim3(2048), dim3(256), 0, stream>>>(x, Wqkv, Xb, Wb);
  qkv_gemm<<<dim3(768), dim3(256), 0, stream>>>(Xb, Wb, bias, Qb, Kb, Vt);
  attn_fwd<<<dim3(512), dim3(256), 0, stream>>>(Qb, Kb, Vt, out);
}

// Round 17
// 103.843 us; speedup vs baseline: 1.3310x; 1.3310x over previous
//
#include <hip/hip_runtime.h>

// Problem dims
constexpr int SEQ   = 2048;
constexpr int BATCH = 2;
constexpr int EMB   = 1024;
constexpr int NH    = 16;
constexpr int HDIM  = 64;
constexpr int MROWS = SEQ * BATCH;   // 4096
constexpr int KDIM  = EMB;           // 1024
constexpr int NCOLS = 3 * EMB;       // 3072

typedef __bf16 bf16x8 __attribute__((ext_vector_type(8)));
typedef __bf16 bf16x4 __attribute__((ext_vector_type(4)));
typedef float  f32x4  __attribute__((ext_vector_type(4)));
typedef float  f32x16 __attribute__((ext_vector_type(16)));
typedef unsigned int u32;
typedef unsigned int u32x4 __attribute__((ext_vector_type(4)));

__device__ __forceinline__ u32 cvt_pk_bf16(float lo, float hi) {
  u32 r;
  asm("v_cvt_pk_bf16_f32 %0, %1, %2" : "=v"(r) : "v"(lo), "v"(hi));
  return r;
}
__device__ __forceinline__ void pl32_swap(u32& a, u32& b) {
  asm("v_permlane32_swap_b32 %0, %1" : "+v"(a), "+v"(b));
}
// async global->LDS, 16B per lane; LDS dest = wave-uniform base + lane*16
__device__ __forceinline__ void g2l16(const __bf16* g, __bf16* l) {
  __builtin_amdgcn_global_load_lds(
      (const __attribute__((address_space(1))) void*)g,
      (__attribute__((address_space(3))) void*)l, 16, 0, 0);
}

// ---------------------------------------------------------------------------
// fp32 -> bf16 cast for BOTH x and Wqkv in one launch
// ---------------------------------------------------------------------------
constexpr int N4X = (MROWS * KDIM) / 4;   // 1048576
constexpr int N4W = (NCOLS * KDIM) / 4;   // 786432
__global__ __launch_bounds__(256) void cvt_all(
    const float* __restrict__ x, const float* __restrict__ Wq,
    __bf16* __restrict__ Xb, __bf16* __restrict__ Wb) {
  int stride = gridDim.x * blockDim.x;
  for (int i = blockIdx.x * blockDim.x + threadIdx.x; i < N4X + N4W; i += stride) {
    const float4 v = (i < N4X) ? reinterpret_cast<const float4*>(x)[i]
                               : reinterpret_cast<const float4*>(Wq)[i - N4X];
    bf16x4 o;
    o[0] = (__bf16)v.x; o[1] = (__bf16)v.y; o[2] = (__bf16)v.z; o[3] = (__bf16)v.w;
    if (i < N4X) reinterpret_cast<bf16x4*>(Xb)[i] = o;
    else         reinterpret_cast<bf16x4*>(Wb)[i - N4X] = o;
  }
}

// ---------------------------------------------------------------------------
// QKV projection (R4/R9-exact, verified ~34us: BK=32, 2-phase dbuf
// gload_lds staging, 4x24 XCD chunking, launch_bounds(256,4) — NOTE: (256,5)
// squeezed VGPR to 48 and spilled acc[4][4] to scratch (R16, 87us).
// ---------------------------------------------------------------------------
__global__ __launch_bounds__(256, 4) void qkv_gemm(
    const __bf16* __restrict__ Xb, const __bf16* __restrict__ Wb,
    const float* __restrict__ bqkv,
    __bf16* __restrict__ Qb, __bf16* __restrict__ Kb, __bf16* __restrict__ Vt) {
  __shared__ __attribute__((aligned(16))) __bf16 Al[2][128 * 32];
  __shared__ __attribute__((aligned(16))) __bf16 Bl[2][128 * 32];

  const int tid  = threadIdx.x;
  const int lane = tid & 63;
  const int w    = tid >> 6;
  const int wm   = w >> 1, wn = w & 1;

  // bijective XCD chunking (R4/R9-verified): 768 blocks, 96 per XCD = 4x24
  const int bid  = blockIdx.x;
  const int wgid = (bid & 7) * 96 + (bid >> 3);
  const int nx   = wgid % 24;
  const int nyy  = wgid / 24;
  const int m0   = nyy * 128;
  const int n0   = nx * 128;

  f32x4 acc[4][4] = {};

  auto stage = [&](int buf, int kt) {
#pragma unroll
    for (int c = 0; c < 2; ++c) {
      const int u   = (w * 2 + c) * 64 + lane;
      const int row = u >> 2;
      const int sc  = ((u & 3) ^ ((row >> 1) & 3)) * 8;
      g2l16(&Xb[(size_t)(m0 + row) * KDIM + kt * 32 + sc], &Al[buf][(w * 2 + c) * 512]);
      g2l16(&Wb[(size_t)(n0 + row) * KDIM + kt * 32 + sc], &Bl[buf][(w * 2 + c) * 512]);
    }
  };

  stage(0, 0);
  __syncthreads();

  const int l15 = lane & 15, hi4 = lane >> 4;
  const int cswz = (hi4 ^ ((l15 >> 1) & 3)) * 8;

  for (int kt = 0; kt < KDIM / 32; ++kt) {
    const int buf = kt & 1;
    if (kt + 1 < KDIM / 32) stage(buf ^ 1, kt + 1);

    bf16x8 af[4], bfr[4];
#pragma unroll
    for (int i = 0; i < 4; ++i) {
      af[i]  = *reinterpret_cast<const bf16x8*>(&Al[buf][(wm * 64 + i * 16 + l15) * 32 + cswz]);
      bfr[i] = *reinterpret_cast<const bf16x8*>(&Bl[buf][(wn * 64 + i * 16 + l15) * 32 + cswz]);
    }
    __builtin_amdgcn_s_setprio(1);
#pragma unroll
    for (int i = 0; i < 4; ++i)
#pragma unroll
      for (int j = 0; j < 4; ++j)
        acc[i][j] = __builtin_amdgcn_mfma_f32_16x16x32_bf16(af[i], bfr[j], acc[i][j], 0, 0, 0);
    __builtin_amdgcn_s_setprio(0);
    __syncthreads();
  }

  const float QSCALE = 0.18033688011112042f;  // 0.125 * log2(e)
#pragma unroll
  for (int j = 0; j < 4; ++j) {
    const int f    = n0 + wn * 64 + j * 16 + l15;
    const float bias = bqkv[f];
    const int sec  = f >> 10;
    const int hd   = f & 1023;
    const int h    = hd >> 6, d = hd & 63;
#pragma unroll
    for (int i = 0; i < 4; ++i) {
#pragma unroll
      for (int r = 0; r < 4; ++r) {
        const int mm = m0 + wm * 64 + i * 16 + hi4 * 4 + r;
        const int s_ = mm >> 1, b_ = mm & 1;
        const int bh = b_ * NH + h;
        const float val = acc[i][j][r] + bias;
        if (sec == 0) {
          Qb[((size_t)bh * SEQ + s_) * HDIM + d] = (__bf16)(val * QSCALE);
        } else if (sec == 1) {
          Kb[((size_t)bh * SEQ + s_) * HDIM + d] = (__bf16)val;
        } else {
          Vt[((size_t)bh * HDIM + d) * SEQ + s_] = (__bf16)val;
        }
      }
    }
  }
}

// ---------------------------------------------------------------------------
// Flash attention (R12-exact, verified 57.0us / absmax 0.0029): 4 waves x
// 32 q-rows, KVBLK=64 double-buffered gload_lds staging, setprio fences
// (load-bearing — R8), max-free softmax + ones-row MFMA denominator.
// ---------------------------------------------------------------------------
__global__ __launch_bounds__(256) void attn_fwd(
    const __bf16* __restrict__ Qb, const __bf16* __restrict__ Kb,
    const __bf16* __restrict__ Vt, float* __restrict__ out) {
  __shared__ __attribute__((aligned(16))) __bf16 lds[16384];  // 2 x (K 8KB + V 8KB)

  const int tid  = threadIdx.x;
  const int lane = tid & 63;
  const int w    = tid >> 6;   // 0..3
  const int lq   = lane & 31;
  const int hi   = lane >> 5;

  // bijective XCD swizzle: 512 blocks, 64 per XCD -> 4 consecutive bh per XCD
  const int bid  = blockIdx.x;
  const int wgid = (bid & 7) * 64 + (bid >> 3);
  const int qi   = wgid & 15;
  const int bh   = wgid >> 4;
  const int b_   = bh >> 4, h = bh & 15;
  const int q0   = qi * 128 + w * 32;

  const __bf16* Qp = Qb + (size_t)bh * SEQ * HDIM;
  const __bf16* Kp = Kb + (size_t)bh * SEQ * HDIM;
  const __bf16* Vp = Vt + (size_t)bh * HDIM * SEQ;

  // Q persistent: QK^T B-operand, col q=lane&31, k(d)=ks*16+hi*8+j
  bf16x8 qf[4];
#pragma unroll
  for (int ks = 0; ks < 4; ++ks)
    qf[ks] = *reinterpret_cast<const bf16x8*>(&Qp[(size_t)(q0 + lq) * HDIM + ks * 16 + hi * 8]);

  // all-ones A-operand for the denominator MFMA
  bf16x8 ones;
#pragma unroll
  for (int i = 0; i < 8; ++i) ones[i] = (__bf16)1.0f;

  f32x16 acc0 = {}, acc1 = {}, accL = {};

  auto stage = [&](int b, int t0) {
#pragma unroll
    for (int c = 0; c < 2; ++c) {
      const int u   = (w * 2 + c) * 64 + lane;            // 0..511 chunks
      const int row = u >> 3;
      const int sc  = ((u & 7) * 8) ^ ((row & 7) << 3);
      g2l16(Kp + (size_t)(t0 + row) * HDIM + sc, lds + b * 8192 + (w * 2 + c) * 512);
      g2l16(Vp + (size_t)row * SEQ + t0 + sc,    lds + b * 8192 + 4096 + (w * 2 + c) * 512);
    }
  };

  stage(0, 0);
  __syncthreads();
  int cur = 0;

  for (int t0 = 0; t0 < SEQ; t0 += 64) {
    if (t0 + 64 < SEQ) stage(cur ^ 1, t0 + 64);  // prefetch flies under compute
    const __bf16* kb = lds + cur * 8192;
    const __bf16* vb = kb + 4096;

    // ---- S = K·Q^T : two 32x32 t-blocks, 4 k-steps over d ----
    f32x16 S0 = {}, S1 = {};
    __builtin_amdgcn_s_setprio(1);
#pragma unroll
    for (int ks = 0; ks < 4; ++ks) {
      const int colb = ks * 16 + hi * 8;
      bf16x8 k0 = *reinterpret_cast<const bf16x8*>(&kb[lq * 64        + (colb ^ ((lq & 7) << 3))]);
      bf16x8 k1 = *reinterpret_cast<const bf16x8*>(&kb[(32 + lq) * 64 + (colb ^ ((lq & 7) << 3))]);
      S0 = __builtin_amdgcn_mfma_f32_32x32x16_bf16(k0, qf[ks], S0, 0, 0, 0);
      S1 = __builtin_amdgcn_mfma_f32_32x32x16_bf16(k1, qf[ks], S1, 0, 0, 0);
    }
    __builtin_amdgcn_s_setprio(0);

    // ---- max-free softmax: P = exp2(S) (no sums — MFMA computes l) ----
#pragma unroll
    for (int i = 0; i < 16; ++i) S0[i] = __builtin_amdgcn_exp2f(S0[i]);
#pragma unroll
    for (int i = 0; i < 16; ++i) S1[i] = __builtin_amdgcn_exp2f(S1[i]);

    // ---- P -> bf16 B-fragments for PV (cvt_pk + permlane32_swap) ----
    bf16x8 pw[4];
    {
      auto mk = [&](const f32x16& P, bf16x8* dst) {
#pragma unroll
        for (int kk = 0; kk < 2; ++kk) {
          u32 a0 = cvt_pk_bf16(P[kk * 8 + 0], P[kk * 8 + 1]);
          u32 b0 = cvt_pk_bf16(P[kk * 8 + 4], P[kk * 8 + 5]);
          u32 a1 = cvt_pk_bf16(P[kk * 8 + 2], P[kk * 8 + 3]);
          u32 b1 = cvt_pk_bf16(P[kk * 8 + 6], P[kk * 8 + 7]);
          pl32_swap(a0, b0);
          pl32_swap(a1, b1);
          u32x4 wv; wv[0] = a0; wv[1] = a1; wv[2] = b0; wv[3] = b1;
          dst[kk] = __builtin_bit_cast(bf16x8, wv);
        }
      };
      mk(S0, &pw[0]);
      mk(S1, &pw[2]);
    }

    // ---- O^T += V^T·P^T and l += 1·P^T : 4 k-steps over t ----
    __builtin_amdgcn_s_setprio(1);
#pragma unroll
    for (int ks = 0; ks < 4; ++ks) {
      const int colb = ks * 16 + hi * 8;
      bf16x8 v0 = *reinterpret_cast<const bf16x8*>(&vb[lq * 64        + (colb ^ ((lq & 7) << 3))]);
      bf16x8 v1 = *reinterpret_cast<const bf16x8*>(&vb[(32 + lq) * 64 + (colb ^ ((lq & 7) << 3))]);
      acc0 = __builtin_amdgcn_mfma_f32_32x32x16_bf16(v0, pw[ks], acc0, 0, 0, 0);
      acc1 = __builtin_amdgcn_mfma_f32_32x32x16_bf16(v1, pw[ks], acc1, 0, 0, 0);
      accL = __builtin_amdgcn_mfma_f32_32x32x16_bf16(ones, pw[ks], accL, 0, 0, 0);
    }
    __builtin_amdgcn_s_setprio(0);

    __syncthreads();  // readers done with cur + prefetch arrived
    cur ^= 1;
  }

  // ---- epilogue: accL[0] == l[q] exactly; no shfl needed ----
  const float inv = 1.0f / accL[0];
  const int s_ = q0 + lq;
  float* op = out + ((size_t)s_ * BATCH + b_) * EMB + h * HDIM;
#pragma unroll
  for (int rr = 0; rr < 4; ++rr) {
    float4 o0 = {acc0[4 * rr] * inv, acc0[4 * rr + 1] * inv,
                 acc0[4 * rr + 2] * inv, acc0[4 * rr + 3] * inv};
    *reinterpret_cast<float4*>(&op[8 * rr + 4 * hi]) = o0;
    float4 o1 = {acc1[4 * rr] * inv, acc1[4 * rr + 1] * inv,
                 acc1[4 * rr + 2] * inv, acc1[4 * rr + 3] * inv};
    *reinterpret_cast<float4*>(&op[8 * rr + 4 * hi + 32]) = o1;
  }
}

// ---------------------------------------------------------------------------
extern "C" void kernel_launch(void* const* d_in, const int* in_sizes, int n_in,
                              void* d_out, int out_size, void* d_ws, size_t ws_size,
                              hipStream_t stream) {
  (void)in_sizes; (void)n_in; (void)out_size; (void)ws_size;
  const float* x    = (const float*)d_in[0];
  const float* Wqkv = (const float*)d_in[1];
  const float* bias = (const float*)d_in[2];
  float* out = (float*)d_out;

  char* ws = (char*)d_ws;
  __bf16* Xb = (__bf16*)(ws);                 //  8 MB  [M][K]
  __bf16* Wb = (__bf16*)(ws + 8388608);       //  6 MB  [N][K]
  __bf16* Qb = (__bf16*)(ws + 14680064);      //  8 MB  [b,h,s,d] (pre-scaled)
  __bf16* Kb = (__bf16*)(ws + 23068672);      //  8 MB  [b,h,s,d]
  __bf16* Vt = (__bf16*)(ws + 31457280);      //  8 MB  [b,h,d,s]

  cvt_all<<<dim3(2048), dim3(256), 0, stream>>>(x, Wqkv, Xb, Wb);
  qkv_gemm<<<dim3(768), dim3(256), 0, stream>>>(Xb, Wb, bias, Qb, Kb, Vt);
  attn_fwd<<<dim3(512), dim3(256), 0, stream>>>(Qb, Kb, Vt, out);
}